// Round 9
// baseline (565.745 us; speedup 1.0000x reference)
//
#include <hip/hip_runtime.h>
#include <hip/hip_bf16.h>
#include <hip/hip_fp16.h>

// ---------------------------------------------------------------------------
// GNN: h = relu(GCN(x)); h = relu(GAT(h)); h = relu(GCN(h)); h = relu(GAT(h));
//      z = h @ Wo + bo.  Outputs: [h (N*128), z (N*64)] fp32.
// R9: aggregation split into (a) per-edge weight precompute (coalesced) and
//     (b) a unified, feature-SLICED gather: 4 column-slices of 32 cols
//     (3.2 MB fp16 each), slice-major grid order -> the active slice is
//     L2-resident in every XCD (gathers were MSHR x latency bound at ~600cy
//     mixed L2/L3; slicing cuts latency to ~L2-hit). One 64B line per edge
//     per slice, 16 edges per load instruction. GEMMs: R8 fp16 MFMA.
// ---------------------------------------------------------------------------

#define WAVE 64
#define BK 256        // nodes per bucket
#define CHUNK 4096    // edges per k_bscatter block

typedef _Float16 f16x8 __attribute__((ext_vector_type(8)));
typedef float f32x4 __attribute__((ext_vector_type(4)));

__global__ void k_zero_i32(int* __restrict__ p, int n) {
    int i = blockIdx.x * 256 + threadIdx.x;
    if (i < n) p[i] = 0;
}

// ------------------------------ graph build --------------------------------
// edge e in [0,E): (s,d) = (ei[e], ei[E+e]); e in [E,Et): self-loop (e-E,e-E)

__global__ __launch_bounds__(256) void k_bhist(
    const int* __restrict__ ei, int* __restrict__ bcnt,
    int E, int Et, int nbuck) {
    __shared__ int hist[256];
    int tid = threadIdx.x;
    if (tid < nbuck) hist[tid] = 0;
    __syncthreads();
    for (int e = blockIdx.x * 256 + tid; e < Et; e += gridDim.x * 256) {
        int d = (e < E) ? ei[E + e] : (e - E);
        atomicAdd(&hist[d >> 8], 1);
    }
    __syncthreads();
    if (tid < nbuck && hist[tid] > 0) atomicAdd(&bcnt[tid], hist[tid]);
}

__global__ void k_bscan(const int* __restrict__ bcnt, int* __restrict__ bbase,
                        int* __restrict__ bcur, int nbuck) {
    __shared__ int tmp[256];
    int tid = threadIdx.x;
    int v = (tid < nbuck) ? bcnt[tid] : 0;
    tmp[tid] = v;
    __syncthreads();
    for (int off = 1; off < 256; off <<= 1) {
        int t = (tid >= off) ? tmp[tid - off] : 0;
        __syncthreads();
        tmp[tid] += t;
        __syncthreads();
    }
    if (tid < nbuck) {
        int excl = tmp[tid] - v;
        bbase[tid] = excl;
        bcur[tid] = excl;
        if (tid == nbuck - 1) bbase[nbuck] = tmp[tid];
    }
}

__global__ __launch_bounds__(256) void k_bscatter(
    const int* __restrict__ ei, int* __restrict__ bcur,
    int2* __restrict__ ebuf, int E, int Et, int nbuck) {
    __shared__ int hist[256];
    __shared__ int base[256];
    __shared__ int off[256];
    constexpr int PT = CHUNK / 256;   // 16 edges per thread
    int tid = threadIdx.x;
    int cb = blockIdx.x * CHUNK;
    if (tid < nbuck) { hist[tid] = 0; off[tid] = 0; }
    __syncthreads();

    int sv[PT], dv[PT];
#pragma unroll
    for (int i = 0; i < PT; ++i) {
        int e = cb + i * 256 + tid;
        int s = 0, d = -1;
        if (e < Et) {
            if (e < E) { s = ei[e]; d = ei[E + e]; }
            else       { s = d = e - E; }
            atomicAdd(&hist[d >> 8], 1);
        }
        sv[i] = s; dv[i] = d;
    }
    __syncthreads();
    if (tid < nbuck && hist[tid] > 0)
        base[tid] = atomicAdd(&bcur[tid], hist[tid]);
    __syncthreads();
#pragma unroll
    for (int i = 0; i < PT; ++i) {
        if (dv[i] >= 0) {
            int b = dv[i] >> 8;
            int pos = base[b] + atomicAdd(&off[b], 1);
            ebuf[pos] = make_int2(sv[i], dv[i]);
        }
    }
}

__global__ __launch_bounds__(256) void k_csr(
    const int2* __restrict__ ebuf, const int* __restrict__ bbase,
    int* __restrict__ rowp, float* __restrict__ inv, int* __restrict__ esrc,
    int Nn, int Et) {
    __shared__ int hist[256];
    __shared__ int scan[256];
    __shared__ int cur[256];
    int tid = threadIdx.x;
    int b = blockIdx.x;
    int bb = bbase[b], cnt = bbase[b + 1] - bb;
    hist[tid] = 0;
    __syncthreads();
    for (int t = tid; t < cnt; t += 256)
        atomicAdd(&hist[ebuf[bb + t].y & 255], 1);
    __syncthreads();
    int v = hist[tid];
    scan[tid] = v;
    __syncthreads();
    for (int o = 1; o < 256; o <<= 1) {
        int t = (tid >= o) ? scan[tid - o] : 0;
        __syncthreads();
        scan[tid] += t;
        __syncthreads();
    }
    int excl = scan[tid] - v;
    int node = b * BK + tid;
    if (node < Nn) {
        rowp[node] = bb + excl;
        inv[node] = rsqrtf((float)v);
    }
    cur[tid] = excl;
    if (b == 0 && tid == 0) rowp[Nn] = Et;
    __syncthreads();
    for (int t = tid; t < cnt; t += 256) {
        int2 e = ebuf[bb + t];
        int pos = bb + atomicAdd(&cur[e.y & 255], 1);
        esrc[pos] = e.x;
    }
}

// -------------------- weight convert (fp32 -> fp16, transposed) ------------
// Wt layout: [0]W1t [16384]Wg1t [32768]W2t [49152]Wg2t [65536]Wot(64x128)

__global__ void k_wcvt(const float* __restrict__ W1, const float* __restrict__ Wg1,
                       const float* __restrict__ W2, const float* __restrict__ Wg2,
                       const float* __restrict__ Wo, __half* __restrict__ Wt) {
    int i = blockIdx.x * 256 + threadIdx.x;   // 73728 total
    if (i < 65536) {
        int w = i >> 14;
        int j = i & 16383;
        int n = j >> 7, k = j & 127;
        const float* W = (w == 0) ? W1 : (w == 1) ? Wg1 : (w == 2) ? W2 : Wg2;
        Wt[i] = __float2half(W[k * 128 + n]);
    } else if (i < 73728) {
        int j = i - 65536;
        int n = j >> 7, k = j & 127;
        Wt[65536 + j] = __float2half(Wo[k * 64 + n]);
    }
}

// ------------------------------ MFMA GEMM ----------------------------------
// (unchanged from R8) out[M x NC] = A(fp32) @ W(fp16 Wt[n][k]); fp32 accum;
// optional fused GAT alpha logits from the fp32 accumulators.

template <int NC, typename OT>
__global__ __launch_bounds__(256) void gemm_mfma(
    const float* __restrict__ A, const __half* __restrict__ Wt,
    const float* __restrict__ bias, OT* __restrict__ out,
    const float* __restrict__ asrc, const float* __restrict__ adst,
    float* __restrict__ alS, float* __restrict__ alD, int M) {
    constexpr int NT = NC / 16;
    constexpr int LDW = 136;
    __shared__ _Float16 Wl[NC * LDW];
    const int tid = threadIdx.x;
    const int wv = tid >> 6, lane = tid & 63;
    const int m16 = lane & 15, quad = lane >> 4;

    for (int i = tid; i < NC * 16; i += 256) {
        int r = i >> 4, c8 = i & 15;
        *(float4*)(&Wl[r * LDW + c8 * 8]) =
            *(const float4*)((const _Float16*)Wt + r * 128 + c8 * 8);
    }
    __syncthreads();

    const int row0 = blockIdx.x * 128 + wv * 32;

    f16x8 af[2][4];
#pragma unroll
    for (int mt = 0; mt < 2; ++mt) {
        int row = row0 + mt * 16 + m16;
        if (row > M - 1) row = M - 1;
        const float* ap = A + (size_t)row * 128 + quad * 8;
#pragma unroll
        for (int ks = 0; ks < 4; ++ks) {
            float4 lo = *(const float4*)(ap + ks * 32);
            float4 hi = *(const float4*)(ap + ks * 32 + 4);
            f16x8 v;
            v[0] = (_Float16)lo.x; v[1] = (_Float16)lo.y;
            v[2] = (_Float16)lo.z; v[3] = (_Float16)lo.w;
            v[4] = (_Float16)hi.x; v[5] = (_Float16)hi.y;
            v[6] = (_Float16)hi.z; v[7] = (_Float16)hi.w;
            af[mt][ks] = v;
        }
    }

    f32x4 acc[2][NT];
#pragma unroll
    for (int mt = 0; mt < 2; ++mt)
#pragma unroll
        for (int nt = 0; nt < NT; ++nt)
            acc[mt][nt] = (f32x4){0.f, 0.f, 0.f, 0.f};

#pragma unroll
    for (int ks = 0; ks < 4; ++ks) {
#pragma unroll
        for (int nt = 0; nt < NT; ++nt) {
            f16x8 bf = *(const f16x8*)(&Wl[(nt * 16 + m16) * LDW + ks * 32 + quad * 8]);
            acc[0][nt] = __builtin_amdgcn_mfma_f32_16x16x32_f16(
                af[0][ks], bf, acc[0][nt], 0, 0, 0);
            acc[1][nt] = __builtin_amdgcn_mfma_f32_16x16x32_f16(
                af[1][ks], bf, acc[1][nt], 0, 0, 0);
        }
    }

    if (asrc) {
        float sa[NT], da[NT];
#pragma unroll
        for (int nt = 0; nt < NT; ++nt) {
            sa[nt] = asrc[nt * 16 + m16];
            da[nt] = adst[nt * 16 + m16];
        }
#pragma unroll
        for (int mt = 0; mt < 2; ++mt) {
#pragma unroll
            for (int r = 0; r < 4; ++r) {
                float s = 0.f, d = 0.f;
#pragma unroll
                for (int nt = 0; nt < NT; ++nt) {
                    s = fmaf(acc[mt][nt][r], sa[nt], s);
                    d = fmaf(acc[mt][nt][r], da[nt], d);
                }
#pragma unroll
                for (int off = 8; off > 0; off >>= 1) {
                    s += __shfl_xor(s, off);
                    d += __shfl_xor(d, off);
                }
                int row = row0 + mt * 16 + quad * 4 + r;
                if (m16 == 0 && row < M) { alS[row] = s; alD[row] = d; }
            }
        }
    }

#pragma unroll
    for (int mt = 0; mt < 2; ++mt) {
#pragma unroll
        for (int nt = 0; nt < NT; ++nt) {
#pragma unroll
            for (int r = 0; r < 4; ++r) {
                int row = row0 + mt * 16 + quad * 4 + r;
                if (row < M) {
                    float v = acc[mt][nt][r];
                    int col = nt * 16 + m16;
                    if constexpr (sizeof(OT) == 2) {
                        ((__half*)out)[(size_t)row * NC + col] = __float2half(v);
                    } else {
                        ((float*)out)[(size_t)row * NC + col] = v + bias[col];
                    }
                }
            }
        }
    }
}

// ------------------------- per-edge weight precompute -----------------------

// GCN coefs (graph-only, computed once): ew[e] = inv[src]*inv[dst]
__global__ __launch_bounds__(256) void k_ewg(
    const int* __restrict__ rowp, const int* __restrict__ esrc,
    const float* __restrict__ inv, float* __restrict__ ew, int Nn) {
    int gid = blockIdx.x * 256 + threadIdx.x;
    int n = gid >> 6, lane = gid & 63;
    if (n >= Nn) return;
    int beg = rowp[n], end = rowp[n + 1];
    float invd = inv[n];
    for (int e = beg + lane; e < end; e += WAVE)
        ew[e] = invd * inv[esrc[e]];
}

// GAT softmax weights per edge (wave per node; R6-proven fast path)
__global__ __launch_bounds__(256) void k_ewa(
    const int* __restrict__ rowp, const int* __restrict__ esrc,
    const float* __restrict__ alS, const float* __restrict__ alD,
    float* __restrict__ ew, int Nn) {
    int gid = blockIdx.x * 256 + threadIdx.x;
    int n = gid >> 6, lane = gid & 63;
    if (n >= Nn) return;
    int beg = rowp[n], end = rowp[n + 1];
    int deg = end - beg;
    float adn = alD[n];

    if (deg <= WAVE) {
        bool vld = (lane < deg);
        float v = -1e30f;
        if (vld) {
            float t = alS[esrc[beg + lane]] + adn;
            v = (t > 0.f) ? t : 0.2f * t;
        }
        float m = v;
#pragma unroll
        for (int off = 32; off > 0; off >>= 1) m = fmaxf(m, __shfl_xor(m, off));
        float ex = vld ? __expf(v - m) : 0.f;
        float ssum = ex;
#pragma unroll
        for (int off = 32; off > 0; off >>= 1) ssum += __shfl_xor(ssum, off);
        if (vld) ew[beg + lane] = ex * (1.f / ssum);
    } else {
        float m = -1e30f, ssum = 0.f;
        for (int e = beg + lane; e < end; e += WAVE) {
            float v = alS[esrc[e]] + adn;
            v = (v > 0.f) ? v : 0.2f * v;
            float mn = fmaxf(m, v);
            ssum = ssum * __expf(m - mn) + __expf(v - mn);
            m = mn;
        }
#pragma unroll
        for (int off = 32; off > 0; off >>= 1) {
            float mo = __shfl_xor(m, off);
            float so = __shfl_xor(ssum, off);
            float mn = fmaxf(m, mo);
            ssum = ssum * __expf(m - mn) + so * __expf(mo - mn);
            m = mn;
        }
        float rden = 1.f / ssum;
        for (int e = beg + lane; e < end; e += WAVE) {
            float v = alS[esrc[e]] + adn;
            v = (v > 0.f) ? v : 0.2f * v;
            ew[e] = __expf(v - m) * rden;
        }
    }
}

// ------------------------- sliced gather (GCN & GAT) ------------------------
// Grid: slice-major (slice = blockIdx / nodeBlk) so the active 3.2 MB xw
// column-slice stays L2-resident chip-wide. Wave per (node, slice):
// 16 groups x 4 lanes; group g handles one edge per round (16 edges/round,
// one dwordx4 per lane = 64 B line per edge-slice). Weights from ew[] --
// coalesced. All shfls in uniform control flow; invalid lanes carry w=0.

__global__ __launch_bounds__(256) void k_gather(
    const __half* __restrict__ xw, const int* __restrict__ rowp,
    const int* __restrict__ esrc, const float* __restrict__ ew,
    const float* __restrict__ bias, float* __restrict__ out,
    int Nn, int nodeBlk) {
    int s = blockIdx.x / nodeBlk;
    int nb = blockIdx.x - s * nodeBlk;
    int wv = threadIdx.x >> 6, lane = threadIdx.x & 63;
    int n = nb * 4 + wv;
    if (n >= Nn) return;
    int g = lane >> 2, cq = lane & 3;
    int beg = rowp[n], end = rowp[n + 1];
    const __half* xs = xw + s * 32 + cq * 8;

    float acc[8] = {0.f, 0.f, 0.f, 0.f, 0.f, 0.f, 0.f, 0.f};
    for (int base = beg; base < end; base += WAVE) {
        int c = end - base;            // uniform (may exceed 64)
        int e = base + lane;
        bool vld = (e < end);
        int sid = vld ? esrc[e] : 0;
        float w = vld ? ew[e] : 0.f;
        float4 x[4];
        float wg[4];
#pragma unroll
        for (int r = 0; r < 4; ++r) {
            if (r * 16 < c) {          // uniform guard
                int idx = r * 16 + g;
                int sg = __shfl(sid, idx);
                wg[r] = __shfl(w, idx);
                x[r] = *(const float4*)(xs + (size_t)sg * 128);
            }
        }
#pragma unroll
        for (int r = 0; r < 4; ++r) {
            if (r * 16 < c) {
                const __half2* h2 = (const __half2*)&x[r];
#pragma unroll
                for (int i = 0; i < 4; ++i) {
                    float2 cc = __half22float2(h2[i]);
                    acc[2 * i]     = fmaf(wg[r], cc.x, acc[2 * i]);
                    acc[2 * i + 1] = fmaf(wg[r], cc.y, acc[2 * i + 1]);
                }
            }
        }
    }
    // reduce across the 16 groups (lanes differing in bits 2..5)
#pragma unroll
    for (int i = 0; i < 8; ++i) {
        acc[i] += __shfl_xor(acc[i], 4);
        acc[i] += __shfl_xor(acc[i], 8);
        acc[i] += __shfl_xor(acc[i], 16);
        acc[i] += __shfl_xor(acc[i], 32);
    }
    if (g == 0) {
        int col = s * 32 + cq * 8;
        float4 b0 = *(const float4*)(bias + col);
        float4 b1 = *(const float4*)(bias + col + 4);
        float4 r0, r1;
        r0.x = fmaxf(acc[0] + b0.x, 0.f);
        r0.y = fmaxf(acc[1] + b0.y, 0.f);
        r0.z = fmaxf(acc[2] + b0.z, 0.f);
        r0.w = fmaxf(acc[3] + b0.w, 0.f);
        r1.x = fmaxf(acc[4] + b1.x, 0.f);
        r1.y = fmaxf(acc[5] + b1.y, 0.f);
        r1.z = fmaxf(acc[6] + b1.z, 0.f);
        r1.w = fmaxf(acc[7] + b1.w, 0.f);
        *(float4*)(out + (size_t)n * 128 + col)     = r0;
        *(float4*)(out + (size_t)n * 128 + col + 4) = r1;
    }
}

// ------------------------------- launch ------------------------------------

extern "C" void kernel_launch(void* const* d_in, const int* in_sizes, int n_in,
                              void* d_out, int out_size, void* d_ws, size_t ws_size,
                              hipStream_t stream) {
    const float* x   = (const float*)d_in[0];
    const int*   ei  = (const int*)d_in[1];
    const float* W1  = (const float*)d_in[2];
    const float* b1  = (const float*)d_in[3];
    const float* Wg1 = (const float*)d_in[4];
    const float* as1 = (const float*)d_in[5];
    const float* ad1 = (const float*)d_in[6];
    const float* bg1 = (const float*)d_in[7];
    const float* W2  = (const float*)d_in[8];
    const float* b2  = (const float*)d_in[9];
    const float* Wg2 = (const float*)d_in[10];
    const float* as2 = (const float*)d_in[11];
    const float* ad2 = (const float*)d_in[12];
    const float* bg2 = (const float*)d_in[13];
    const float* Wo  = (const float*)d_in[14];
    const float* bo  = (const float*)d_in[15];

    const int Nn = in_sizes[0] / 128;
    const int E  = in_sizes[1] / 2;
    const int Et = E + Nn;
    const int H  = 128;
    const int nbuck = (Nn + BK - 1) / BK;   // 196

    float* outH = (float*)d_out;
    float* outZ = outH + (size_t)Nn * H;

    char* p = (char*)d_ws;
    auto carve = [&](size_t bytes) {
        char* r = p;
        p += (bytes + 255) & ~(size_t)255;
        return r;
    };
    __half* bufA = (__half*)carve((size_t)Nn * H * sizeof(__half));  // xw (fp16)
    __half* Wt   = (__half*)carve((size_t)73728 * sizeof(__half));   // fp16 W^T x5
    float* alS   = (float*)carve((size_t)Nn * sizeof(float));
    float* alD   = (float*)carve((size_t)Nn * sizeof(float));
    float* inv   = (float*)carve((size_t)Nn * sizeof(float));
    int*   rowp  = (int*)carve((size_t)(Nn + 1) * sizeof(int));
    int*   esrc  = (int*)carve((size_t)Et * sizeof(int));
    int2*  ebuf  = (int2*)carve((size_t)Et * sizeof(int2));   // build-only
    int*   bcnt  = (int*)carve((size_t)nbuck * sizeof(int));
    int*   bbase = (int*)carve((size_t)(nbuck + 1) * sizeof(int));
    int*   bcur  = (int*)carve((size_t)nbuck * sizeof(int));
    // ebuf is dead after k_csr -> alias its space for the edge weights
    float* ewG = (float*)ebuf;              // GCN coefs (Et floats)
    float* ewA = (float*)ebuf + Et;         // GAT alphas (Et floats)
    (void)ws_size; (void)n_in; (void)out_size;

    const int nodeW  = (Nn * WAVE + 255) / 256;   // wave-per-node grids
    const int gemmB  = (Nn + 127) / 128;
    const int scatB  = (Et + CHUNK - 1) / CHUNK;
    const int nodeBlk = (Nn + 3) / 4;
    const int gathB  = 4 * nodeBlk;

    // graph build (two-level bucket sort)
    k_zero_i32<<<1, 256, 0, stream>>>(bcnt, nbuck);
    k_bhist<<<104, 256, 0, stream>>>(ei, bcnt, E, Et, nbuck);
    k_bscan<<<1, 256, 0, stream>>>(bcnt, bbase, bcur, nbuck);
    k_bscatter<<<scatB, 256, 0, stream>>>(ei, bcur, ebuf, E, Et, nbuck);
    k_csr<<<nbuck, 256, 0, stream>>>(ebuf, bbase, rowp, inv, esrc, Nn, Et);
    k_wcvt<<<288, 256, 0, stream>>>(W1, Wg1, W2, Wg2, Wo, Wt);
    k_ewg<<<nodeW, 256, 0, stream>>>(rowp, esrc, inv, ewG, Nn);  // after k_csr!

    // L1: GCN
    gemm_mfma<128, __half><<<gemmB, 256, 0, stream>>>(
        x, Wt, nullptr, bufA, nullptr, nullptr, nullptr, nullptr, Nn);
    k_gather<<<gathB, 256, 0, stream>>>(bufA, rowp, esrc, ewG, b1, outH, Nn, nodeBlk);

    // L2: GAT
    gemm_mfma<128, __half><<<gemmB, 256, 0, stream>>>(
        outH, Wt + 16384, nullptr, bufA, as1, ad1, alS, alD, Nn);
    k_ewa<<<nodeW, 256, 0, stream>>>(rowp, esrc, alS, alD, ewA, Nn);
    k_gather<<<gathB, 256, 0, stream>>>(bufA, rowp, esrc, ewA, bg1, outH, Nn, nodeBlk);

    // L3: GCN
    gemm_mfma<128, __half><<<gemmB, 256, 0, stream>>>(
        outH, Wt + 32768, nullptr, bufA, nullptr, nullptr, nullptr, nullptr, Nn);
    k_gather<<<gathB, 256, 0, stream>>>(bufA, rowp, esrc, ewG, b2, outH, Nn, nodeBlk);

    // L4: GAT
    gemm_mfma<128, __half><<<gemmB, 256, 0, stream>>>(
        outH, Wt + 49152, nullptr, bufA, as2, ad2, alS, alD, Nn);
    k_ewa<<<nodeW, 256, 0, stream>>>(rowp, esrc, alS, alD, ewA, Nn);
    k_gather<<<gathB, 256, 0, stream>>>(bufA, rowp, esrc, ewA, bg2, outH, Nn, nodeBlk);

    // head
    gemm_mfma<64, float><<<gemmB, 256, 0, stream>>>(
        outH, Wt + 65536, bo, outZ, nullptr, nullptr, nullptr, nullptr, Nn);
}

// Round 10
// 397.422 us; speedup vs baseline: 1.4235x; 1.4235x over previous
//
#include <hip/hip_runtime.h>
#include <hip/hip_bf16.h>
#include <hip/hip_fp16.h>

// ---------------------------------------------------------------------------
// GNN: h = relu(GCN(x)); h = relu(GAT(h)); h = relu(GCN(h)); h = relu(GAT(h));
//      z = h @ Wo + bo.  Outputs: [h (N*128), z (N*64)] fp32.
// R10: R9's slicing reverted (64B-strided slices occupy 2x cache at 128B
//      lines -> never L2-resident; + 4x VALU overhead). Gather = R8 whole-row
//      quarter-wave pipeline, now with PRECOMPUTED per-edge weights (ew[]):
//      one unified gather kernel for GCN+GAT. GEMM: 64-row blocks (2x grid,
//      ~16 waves/CU) + A-loads issued before W staging (latency overlap).
// ---------------------------------------------------------------------------

#define WAVE 64
#define BK 256        // nodes per bucket
#define CHUNK 4096    // edges per k_bscatter block

typedef _Float16 f16x8 __attribute__((ext_vector_type(8)));
typedef float f32x4 __attribute__((ext_vector_type(4)));

__global__ void k_zero_i32(int* __restrict__ p, int n) {
    int i = blockIdx.x * 256 + threadIdx.x;
    if (i < n) p[i] = 0;
}

// ------------------------------ graph build --------------------------------
// edge e in [0,E): (s,d) = (ei[e], ei[E+e]); e in [E,Et): self-loop (e-E,e-E)

__global__ __launch_bounds__(256) void k_bhist(
    const int* __restrict__ ei, int* __restrict__ bcnt,
    int E, int Et, int nbuck) {
    __shared__ int hist[256];
    int tid = threadIdx.x;
    if (tid < nbuck) hist[tid] = 0;
    __syncthreads();
    for (int e = blockIdx.x * 256 + tid; e < Et; e += gridDim.x * 256) {
        int d = (e < E) ? ei[E + e] : (e - E);
        atomicAdd(&hist[d >> 8], 1);
    }
    __syncthreads();
    if (tid < nbuck && hist[tid] > 0) atomicAdd(&bcnt[tid], hist[tid]);
}

__global__ void k_bscan(const int* __restrict__ bcnt, int* __restrict__ bbase,
                        int* __restrict__ bcur, int nbuck) {
    __shared__ int tmp[256];
    int tid = threadIdx.x;
    int v = (tid < nbuck) ? bcnt[tid] : 0;
    tmp[tid] = v;
    __syncthreads();
    for (int off = 1; off < 256; off <<= 1) {
        int t = (tid >= off) ? tmp[tid - off] : 0;
        __syncthreads();
        tmp[tid] += t;
        __syncthreads();
    }
    if (tid < nbuck) {
        int excl = tmp[tid] - v;
        bbase[tid] = excl;
        bcur[tid] = excl;
        if (tid == nbuck - 1) bbase[nbuck] = tmp[tid];
    }
}

__global__ __launch_bounds__(256) void k_bscatter(
    const int* __restrict__ ei, int* __restrict__ bcur,
    int2* __restrict__ ebuf, int E, int Et, int nbuck) {
    __shared__ int hist[256];
    __shared__ int base[256];
    __shared__ int off[256];
    constexpr int PT = CHUNK / 256;   // 16 edges per thread
    int tid = threadIdx.x;
    int cb = blockIdx.x * CHUNK;
    if (tid < nbuck) { hist[tid] = 0; off[tid] = 0; }
    __syncthreads();

    int sv[PT], dv[PT];
#pragma unroll
    for (int i = 0; i < PT; ++i) {
        int e = cb + i * 256 + tid;
        int s = 0, d = -1;
        if (e < Et) {
            if (e < E) { s = ei[e]; d = ei[E + e]; }
            else       { s = d = e - E; }
            atomicAdd(&hist[d >> 8], 1);
        }
        sv[i] = s; dv[i] = d;
    }
    __syncthreads();
    if (tid < nbuck && hist[tid] > 0)
        base[tid] = atomicAdd(&bcur[tid], hist[tid]);
    __syncthreads();
#pragma unroll
    for (int i = 0; i < PT; ++i) {
        if (dv[i] >= 0) {
            int b = dv[i] >> 8;
            int pos = base[b] + atomicAdd(&off[b], 1);
            ebuf[pos] = make_int2(sv[i], dv[i]);
        }
    }
}

__global__ __launch_bounds__(256) void k_csr(
    const int2* __restrict__ ebuf, const int* __restrict__ bbase,
    int* __restrict__ rowp, float* __restrict__ inv, int* __restrict__ esrc,
    int Nn, int Et) {
    __shared__ int hist[256];
    __shared__ int scan[256];
    __shared__ int cur[256];
    int tid = threadIdx.x;
    int b = blockIdx.x;
    int bb = bbase[b], cnt = bbase[b + 1] - bb;
    hist[tid] = 0;
    __syncthreads();
    for (int t = tid; t < cnt; t += 256)
        atomicAdd(&hist[ebuf[bb + t].y & 255], 1);
    __syncthreads();
    int v = hist[tid];
    scan[tid] = v;
    __syncthreads();
    for (int o = 1; o < 256; o <<= 1) {
        int t = (tid >= o) ? scan[tid - o] : 0;
        __syncthreads();
        scan[tid] += t;
        __syncthreads();
    }
    int excl = scan[tid] - v;
    int node = b * BK + tid;
    if (node < Nn) {
        rowp[node] = bb + excl;
        inv[node] = rsqrtf((float)v);
    }
    cur[tid] = excl;
    if (b == 0 && tid == 0) rowp[Nn] = Et;
    __syncthreads();
    for (int t = tid; t < cnt; t += 256) {
        int2 e = ebuf[bb + t];
        int pos = bb + atomicAdd(&cur[e.y & 255], 1);
        esrc[pos] = e.x;
    }
}

// -------------------- weight convert (fp32 -> fp16, transposed) ------------
// Wt layout: [0]W1t [16384]Wg1t [32768]W2t [49152]Wg2t [65536]Wot(64x128)

__global__ void k_wcvt(const float* __restrict__ W1, const float* __restrict__ Wg1,
                       const float* __restrict__ W2, const float* __restrict__ Wg2,
                       const float* __restrict__ Wo, __half* __restrict__ Wt) {
    int i = blockIdx.x * 256 + threadIdx.x;   // 73728 total
    if (i < 65536) {
        int w = i >> 14;
        int j = i & 16383;
        int n = j >> 7, k = j & 127;
        const float* W = (w == 0) ? W1 : (w == 1) ? Wg1 : (w == 2) ? W2 : Wg2;
        Wt[i] = __float2half(W[k * 128 + n]);
    } else if (i < 73728) {
        int j = i - 65536;
        int n = j >> 7, k = j & 127;
        Wt[65536 + j] = __float2half(Wo[k * 64 + n]);
    }
}

// ------------------------------ MFMA GEMM ----------------------------------
// out[M x NC] = A(fp32 M x 128) @ W(fp16 Wt[n][k]); fp32 accum. Block =
// 4 waves x 16 rows = 64 rows (grid ~782 -> ~16 waves/CU for latency hiding).
// A loads issued BEFORE W staging so global latency overlaps stage+sync.
// B frag from LDS (136-half padded stride). C/D: col=lane&15, row=quad*4+reg.
// If asrc!=null: GAT alpha logits fused from fp32 accumulators.

template <int NC, typename OT>
__global__ __launch_bounds__(256) void gemm_mfma(
    const float* __restrict__ A, const __half* __restrict__ Wt,
    const float* __restrict__ bias, OT* __restrict__ out,
    const float* __restrict__ asrc, const float* __restrict__ adst,
    float* __restrict__ alS, float* __restrict__ alD, int M) {
    constexpr int NT = NC / 16;
    constexpr int LDW = 136;
    __shared__ _Float16 Wl[NC * LDW];
    const int tid = threadIdx.x;
    const int wv = tid >> 6, lane = tid & 63;
    const int m16 = lane & 15, quad = lane >> 4;
    const int row0 = blockIdx.x * 64 + wv * 16;

    // A loads first (independent of LDS staging)
    int row = row0 + m16;
    if (row > M - 1) row = M - 1;
    const float* ap = A + (size_t)row * 128 + quad * 8;
    float4 a32[4][2];
#pragma unroll
    for (int ks = 0; ks < 4; ++ks) {
        a32[ks][0] = *(const float4*)(ap + ks * 32);
        a32[ks][1] = *(const float4*)(ap + ks * 32 + 4);
    }

    // stage W^T to LDS
    for (int i = tid; i < NC * 16; i += 256) {
        int r = i >> 4, c8 = i & 15;
        *(float4*)(&Wl[r * LDW + c8 * 8]) =
            *(const float4*)((const _Float16*)Wt + r * 128 + c8 * 8);
    }
    __syncthreads();

    f16x8 af[4];
#pragma unroll
    for (int ks = 0; ks < 4; ++ks) {
        f16x8 v;
        v[0] = (_Float16)a32[ks][0].x; v[1] = (_Float16)a32[ks][0].y;
        v[2] = (_Float16)a32[ks][0].z; v[3] = (_Float16)a32[ks][0].w;
        v[4] = (_Float16)a32[ks][1].x; v[5] = (_Float16)a32[ks][1].y;
        v[6] = (_Float16)a32[ks][1].z; v[7] = (_Float16)a32[ks][1].w;
        af[ks] = v;
    }

    f32x4 acc[NT];
#pragma unroll
    for (int nt = 0; nt < NT; ++nt) acc[nt] = (f32x4){0.f, 0.f, 0.f, 0.f};

#pragma unroll
    for (int ks = 0; ks < 4; ++ks) {
#pragma unroll
        for (int nt = 0; nt < NT; ++nt) {
            f16x8 bf = *(const f16x8*)(&Wl[(nt * 16 + m16) * LDW + ks * 32 + quad * 8]);
            acc[nt] = __builtin_amdgcn_mfma_f32_16x16x32_f16(af[ks], bf, acc[nt], 0, 0, 0);
        }
    }

    // fused GAT alpha logits: s = xw.asrc, d = xw.adst per row
    if (asrc) {
        float sa[NT], da[NT];
#pragma unroll
        for (int nt = 0; nt < NT; ++nt) {
            sa[nt] = asrc[nt * 16 + m16];
            da[nt] = adst[nt * 16 + m16];
        }
#pragma unroll
        for (int r = 0; r < 4; ++r) {
            float s = 0.f, d = 0.f;
#pragma unroll
            for (int nt = 0; nt < NT; ++nt) {
                s = fmaf(acc[nt][r], sa[nt], s);
                d = fmaf(acc[nt][r], da[nt], d);
            }
#pragma unroll
            for (int off = 8; off > 0; off >>= 1) {
                s += __shfl_xor(s, off);
                d += __shfl_xor(d, off);
            }
            int orow = row0 + quad * 4 + r;
            if (m16 == 0 && orow < M) { alS[orow] = s; alD[orow] = d; }
        }
    }

#pragma unroll
    for (int nt = 0; nt < NT; ++nt) {
#pragma unroll
        for (int r = 0; r < 4; ++r) {
            int orow = row0 + quad * 4 + r;
            if (orow < M) {
                float v = acc[nt][r];
                int col = nt * 16 + m16;
                if constexpr (sizeof(OT) == 2) {
                    ((__half*)out)[(size_t)orow * NC + col] = __float2half(v);
                } else {
                    ((float*)out)[(size_t)orow * NC + col] = v + bias[col];
                }
            }
        }
    }
}

// ------------------------- per-edge weight precompute -----------------------

// GCN coefs (graph-only, computed once): ew[e] = inv[src]*inv[dst]
__global__ __launch_bounds__(256) void k_ewg(
    const int* __restrict__ rowp, const int* __restrict__ esrc,
    const float* __restrict__ inv, float* __restrict__ ew, int Nn) {
    int gid = blockIdx.x * 256 + threadIdx.x;
    int n = gid >> 6, lane = gid & 63;
    if (n >= Nn) return;
    int beg = rowp[n], end = rowp[n + 1];
    float invd = inv[n];
    for (int e = beg + lane; e < end; e += WAVE)
        ew[e] = invd * inv[esrc[e]];
}

// GAT softmax weights per edge (wave per node)
__global__ __launch_bounds__(256) void k_ewa(
    const int* __restrict__ rowp, const int* __restrict__ esrc,
    const float* __restrict__ alS, const float* __restrict__ alD,
    float* __restrict__ ew, int Nn) {
    int gid = blockIdx.x * 256 + threadIdx.x;
    int n = gid >> 6, lane = gid & 63;
    if (n >= Nn) return;
    int beg = rowp[n], end = rowp[n + 1];
    int deg = end - beg;
    float adn = alD[n];

    if (deg <= WAVE) {
        bool vld = (lane < deg);
        float v = -1e30f;
        if (vld) {
            float t = alS[esrc[beg + lane]] + adn;
            v = (t > 0.f) ? t : 0.2f * t;
        }
        float m = v;
#pragma unroll
        for (int off = 32; off > 0; off >>= 1) m = fmaxf(m, __shfl_xor(m, off));
        float ex = vld ? __expf(v - m) : 0.f;
        float ssum = ex;
#pragma unroll
        for (int off = 32; off > 0; off >>= 1) ssum += __shfl_xor(ssum, off);
        if (vld) ew[beg + lane] = ex * (1.f / ssum);
    } else {
        float m = -1e30f, ssum = 0.f;
        for (int e = beg + lane; e < end; e += WAVE) {
            float v = alS[esrc[e]] + adn;
            v = (v > 0.f) ? v : 0.2f * v;
            float mn = fmaxf(m, v);
            ssum = ssum * __expf(m - mn) + __expf(v - mn);
            m = mn;
        }
#pragma unroll
        for (int off = 32; off > 0; off >>= 1) {
            float mo = __shfl_xor(m, off);
            float so = __shfl_xor(ssum, off);
            float mn = fmaxf(m, mo);
            ssum = ssum * __expf(m - mn) + so * __expf(mo - mn);
            m = mn;
        }
        float rden = 1.f / ssum;
        for (int e = beg + lane; e < end; e += WAVE) {
            float v = alS[esrc[e]] + adn;
            v = (v > 0.f) ? v : 0.2f * v;
            ew[e] = __expf(v - m) * rden;
        }
    }
}

// --------------------------- unified gather --------------------------------
// One wave per destination node (whole 256 B fp16 row). lane = 16*g + q:
// quarter-wave g handles edge j+g of each group of 4; lane owns fp16 features
// 8q..8q+7 (16 B dwordx4). Weights from precomputed ew[] (coalesced).
// INVARIANT: lanes with index >= cnt hold w == 0 and a valid sid (0 ok);
// all guards wave-uniform so shfl always executes with full exec.

__global__ __launch_bounds__(256) void k_gather(
    const __half* __restrict__ xw, const int* __restrict__ rowp,
    const int* __restrict__ esrc, const float* __restrict__ ew,
    const float* __restrict__ bias, float* __restrict__ out, int Nn) {
    int gid = blockIdx.x * 256 + threadIdx.x;
    int n = gid >> 6, lane = gid & 63;
    if (n >= Nn) return;
    int q = lane & 15, g = lane >> 4;
    int beg = rowp[n], end = rowp[n + 1];

    float acc[8] = {0.f, 0.f, 0.f, 0.f, 0.f, 0.f, 0.f, 0.f};
    for (int eb = beg; eb < end; eb += WAVE) {
        int e = eb + lane;
        bool vld = (e < end);
        int sid = vld ? esrc[e] : 0;
        float w = vld ? ew[e] : 0.f;
        int cnt = min(WAVE, end - eb);
        for (int base = 0; base < cnt; base += 32) {
            int c = cnt - base;           // wave-uniform
            float4 x[8];
            float wg[8];
#pragma unroll
            for (int u = 0; u < 8; ++u) {
                if (u * 4 < c) {          // uniform guard
                    int idx = base + 4 * u + g;
                    int s = __shfl(sid, idx);
                    wg[u] = __shfl(w, idx);
                    x[u] = *(const float4*)(xw + (size_t)s * 128 + q * 8);
                }
            }
#pragma unroll
            for (int u = 0; u < 8; ++u) {
                if (u * 4 < c) {          // uniform guard
                    const __half2* h2 = (const __half2*)&x[u];
#pragma unroll
                    for (int i = 0; i < 4; ++i) {
                        float2 cc = __half22float2(h2[i]);
                        acc[2 * i]     = fmaf(wg[u], cc.x, acc[2 * i]);
                        acc[2 * i + 1] = fmaf(wg[u], cc.y, acc[2 * i + 1]);
                    }
                }
            }
        }
    }
#pragma unroll
    for (int i = 0; i < 8; ++i) {
        acc[i] += __shfl_xor(acc[i], 16);
        acc[i] += __shfl_xor(acc[i], 32);
    }
    if (g == 0) {
        float4 b0 = ((const float4*)bias)[q * 2];
        float4 b1 = ((const float4*)bias)[q * 2 + 1];
        float4 r0, r1;
        r0.x = fmaxf(acc[0] + b0.x, 0.f);
        r0.y = fmaxf(acc[1] + b0.y, 0.f);
        r0.z = fmaxf(acc[2] + b0.z, 0.f);
        r0.w = fmaxf(acc[3] + b0.w, 0.f);
        r1.x = fmaxf(acc[4] + b1.x, 0.f);
        r1.y = fmaxf(acc[5] + b1.y, 0.f);
        r1.z = fmaxf(acc[6] + b1.z, 0.f);
        r1.w = fmaxf(acc[7] + b1.w, 0.f);
        float4* orow = (float4*)(out + (size_t)n * 128);
        orow[q * 2]     = r0;
        orow[q * 2 + 1] = r1;
    }
}

// ------------------------------- launch ------------------------------------

extern "C" void kernel_launch(void* const* d_in, const int* in_sizes, int n_in,
                              void* d_out, int out_size, void* d_ws, size_t ws_size,
                              hipStream_t stream) {
    const float* x   = (const float*)d_in[0];
    const int*   ei  = (const int*)d_in[1];
    const float* W1  = (const float*)d_in[2];
    const float* b1  = (const float*)d_in[3];
    const float* Wg1 = (const float*)d_in[4];
    const float* as1 = (const float*)d_in[5];
    const float* ad1 = (const float*)d_in[6];
    const float* bg1 = (const float*)d_in[7];
    const float* W2  = (const float*)d_in[8];
    const float* b2  = (const float*)d_in[9];
    const float* Wg2 = (const float*)d_in[10];
    const float* as2 = (const float*)d_in[11];
    const float* ad2 = (const float*)d_in[12];
    const float* bg2 = (const float*)d_in[13];
    const float* Wo  = (const float*)d_in[14];
    const float* bo  = (const float*)d_in[15];

    const int Nn = in_sizes[0] / 128;
    const int E  = in_sizes[1] / 2;
    const int Et = E + Nn;
    const int H  = 128;
    const int nbuck = (Nn + BK - 1) / BK;   // 196

    float* outH = (float*)d_out;
    float* outZ = outH + (size_t)Nn * H;

    char* p = (char*)d_ws;
    auto carve = [&](size_t bytes) {
        char* r = p;
        p += (bytes + 255) & ~(size_t)255;
        return r;
    };
    __half* bufA = (__half*)carve((size_t)Nn * H * sizeof(__half));  // xw (fp16)
    __half* Wt   = (__half*)carve((size_t)73728 * sizeof(__half));   // fp16 W^T x5
    float* alS   = (float*)carve((size_t)Nn * sizeof(float));
    float* alD   = (float*)carve((size_t)Nn * sizeof(float));
    float* inv   = (float*)carve((size_t)Nn * sizeof(float));
    int*   rowp  = (int*)carve((size_t)(Nn + 1) * sizeof(int));
    int*   esrc  = (int*)carve((size_t)Et * sizeof(int));
    int2*  ebuf  = (int2*)carve((size_t)Et * sizeof(int2));   // build-only
    int*   bcnt  = (int*)carve((size_t)nbuck * sizeof(int));
    int*   bbase = (int*)carve((size_t)(nbuck + 1) * sizeof(int));
    int*   bcur  = (int*)carve((size_t)nbuck * sizeof(int));
    // ebuf is dead after k_csr -> alias its space for the edge weights
    float* ewG = (float*)ebuf;              // GCN coefs (Et floats)
    float* ewA = (float*)ebuf + Et;         // GAT alphas (Et floats)
    (void)ws_size; (void)n_in; (void)out_size;

    const int nodeW = (Nn * WAVE + 255) / 256;    // wave-per-node grids
    const int gemmB = (Nn + 63) / 64;             // 782
    const int scatB = (Et + CHUNK - 1) / CHUNK;

    // graph build (two-level bucket sort)
    k_zero_i32<<<1, 256, 0, stream>>>(bcnt, nbuck);
    k_bhist<<<104, 256, 0, stream>>>(ei, bcnt, E, Et, nbuck);
    k_bscan<<<1, 256, 0, stream>>>(bcnt, bbase, bcur, nbuck);
    k_bscatter<<<scatB, 256, 0, stream>>>(ei, bcur, ebuf, E, Et, nbuck);
    k_csr<<<nbuck, 256, 0, stream>>>(ebuf, bbase, rowp, inv, esrc, Nn, Et);
    k_wcvt<<<288, 256, 0, stream>>>(W1, Wg1, W2, Wg2, Wo, Wt);
    k_ewg<<<nodeW, 256, 0, stream>>>(rowp, esrc, inv, ewG, Nn);  // after k_csr

    // L1: GCN
    gemm_mfma<128, __half><<<gemmB, 256, 0, stream>>>(
        x, Wt, nullptr, bufA, nullptr, nullptr, nullptr, nullptr, Nn);
    k_gather<<<nodeW, 256, 0, stream>>>(bufA, rowp, esrc, ewG, b1, outH, Nn);

    // L2: GAT
    gemm_mfma<128, __half><<<gemmB, 256, 0, stream>>>(
        outH, Wt + 16384, nullptr, bufA, as1, ad1, alS, alD, Nn);
    k_ewa<<<nodeW, 256, 0, stream>>>(rowp, esrc, alS, alD, ewA, Nn);
    k_gather<<<nodeW, 256, 0, stream>>>(bufA, rowp, esrc, ewA, bg1, outH, Nn);

    // L3: GCN
    gemm_mfma<128, __half><<<gemmB, 256, 0, stream>>>(
        outH, Wt + 32768, nullptr, bufA, nullptr, nullptr, nullptr, nullptr, Nn);
    k_gather<<<nodeW, 256, 0, stream>>>(bufA, rowp, esrc, ewG, b2, outH, Nn);

    // L4: GAT
    gemm_mfma<128, __half><<<gemmB, 256, 0, stream>>>(
        outH, Wt + 49152, nullptr, bufA, as2, ad2, alS, alD, Nn);
    k_ewa<<<nodeW, 256, 0, stream>>>(rowp, esrc, alS, alD, ewA, Nn);
    k_gather<<<nodeW, 256, 0, stream>>>(bufA, rowp, esrc, ewA, bg2, outH, Nn);

    // head
    gemm_mfma<64, float><<<gemmB, 256, 0, stream>>>(
        outH, Wt + 65536, bo, outZ, nullptr, nullptr, nullptr, nullptr, Nn);
}